// Round 5
// baseline (5449.773 us; speedup 1.0000x reference)
//
#include <hip/hip_runtime.h>
#include <hip/hip_bf16.h>
#include <math.h>

// ---------------------------------------------------------------------------
// LSTM text classifier forward, MI355X/gfx950.  Round 11.
//
// R10 post-mortem: split-K/lag-1 poll structure is CORRECT (passed, absmax
// = R6) but 4x slower.  Root cause: barrier2 was LDS-only, so the publish
// stores were never force-drained -- a relaxed agent store sits in the CU
// write queue with no urgency; partner polls missed by thousands of cycles
// and 4096 spinning threads saturated L3.  The vmcnt(0) drain in
// __syncthreads IS the publication mechanism, not overhead.
//
// R11 = R10 structure + restored drain:
//  - barrier2 (end of step) = __syncthreads(): publish h(t) is DRAINED
//    before any wave leaves step t.  Consumer first touches h(t) in the
//    middle of step t+1 (a full barrier + own-half MFMA phase later) ->
//    first-poll hit, no retry round trips (R6 burned ~3000 cyc there
//    polling same-step data).
//  - barrier1 (mid-step) stays LDS-only {s_waitcnt lgkmcnt(0); s_barrier}:
//    nothing vmem-outstanding at that point.
//  - Everything else byte-identical to R10: R6-verified epoch-keyed u64
//    {data, data^key} agent atomics, 8 slots, split-K ordering, bounded
//    spin as hang-proofing.
//
// Structure recap: 8 worker blocks = 4 batch-groups x 2 halves (128 units);
// U in AGPRs via "+a" pin + inline-asm MFMA (B from AGPR); h double-
// buffered in LDS; partner blocks b,b^8; blocks with b&4 exit as spares.
//
// MFMA 16x16x32 bf16 layouts (m89/m91):
//   A[m][k]: m=lane&15, k=(lane>>4)*8+j      B[k][n]: n=lane&15, same k
//   C/D:     col=lane&15, row=(lane>>4)*4+reg
// ---------------------------------------------------------------------------

typedef __bf16 bf16_t;
typedef bf16_t bf16x8 __attribute__((ext_vector_type(8)));
typedef bf16_t bf16x4 __attribute__((ext_vector_type(4)));
typedef float  f32x4  __attribute__((ext_vector_type(4)));
typedef unsigned long long u64;

#define T_SZ 512
#define HID 256
#define G4 1024
#define NCLS 20

// workspace layout (bytes)
#define WS_UPACK 0u
#define WS_WPACK (512u * 1024u)
#define WS_HFIN  (1024u * 1024u)                  // 64 KB
#define WS_EXCH  (1536u * 1024u)                  // 512 KB: 8 slots x 4g x 2p x 1024 u64
#define WS_XZ    (2u * 1024u * 1024u)             // 64 MB
// total: 66 MB

// ---------------------------------------------------------------------------
// Pack W and U (f32 [256][1024]) into bf16 B-fragment order:
// frag f = (ntile*8 + kstep)*64 + lane ; element j=0..7
// value = M[kstep*32 + (lane>>4)*8 + j][ntile*16 + (lane&15)]
// ---------------------------------------------------------------------------
__global__ void pack_weights(const float* __restrict__ W, const float* __restrict__ U,
                             bf16_t* __restrict__ Wp, bf16_t* __restrict__ Up) {
    int tid  = blockIdx.x * blockDim.x + threadIdx.x;   // 0..262143
    int j    = tid & 7;
    int lane = (tid >> 3) & 63;
    int ks   = (tid >> 9) & 7;
    int nt   = tid >> 12;
    int row  = ks * 32 + ((lane >> 4) << 3) + j;
    int col  = nt * 16 + (lane & 15);
    Wp[tid] = (bf16_t)W[row * G4 + col];
    Up[tid] = (bf16_t)U[row * G4 + col];
}

// ---------------------------------------------------------------------------
// Phase A: xz = emb[x] @ W + bias, stored bf16 in C-fragment order:
//   xz2[((t*4 + bchunk)*64 + ntile)*64 + lane] = bf16x4 {r=0..3}
// value[r] = z[batch = bchunk*16 + (lane>>4)*4 + r][col = ntile*16 + (lane&15)]
// ---------------------------------------------------------------------------
__global__ __launch_bounds__(256) void xz_gemm(const int* __restrict__ x,
                                               const float* __restrict__ emb,
                                               const bf16_t* __restrict__ Wp,
                                               const float* __restrict__ bias,
                                               bf16x4* __restrict__ xz2) {
    int nb   = blockIdx.x & 7;
    int t    = blockIdx.x >> 3;
    int w    = threadIdx.x >> 6;
    int lane = threadIdx.x & 63;
    int l15  = lane & 15;
    int quad = lane >> 4;

    int b_row = w * 16 + l15;
    int tok   = x[b_row * T_SZ + t];
    const float* erow = emb + (size_t)tok * 256;

    bf16x8 afrag[8];
#pragma unroll
    for (int ks = 0; ks < 8; ks++) {
        const float4* p = (const float4*)(erow + ks * 32 + quad * 8);
        float4 v0 = p[0], v1 = p[1];
        bf16x8 a;
        a[0] = (bf16_t)v0.x; a[1] = (bf16_t)v0.y; a[2] = (bf16_t)v0.z; a[3] = (bf16_t)v0.w;
        a[4] = (bf16_t)v1.x; a[5] = (bf16_t)v1.y; a[6] = (bf16_t)v1.z; a[7] = (bf16_t)v1.w;
        afrag[ks] = a;
    }

    const bf16x8* Wf = (const bf16x8*)Wp;

#pragma unroll
    for (int nt = 0; nt < 8; nt++) {
        int ntg = nb * 8 + nt;
        float bv = bias[ntg * 16 + l15];
        f32x4 acc = {bv, bv, bv, bv};
        const bf16x8* bp = Wf + (size_t)(ntg * 8) * 64 + lane;
#pragma unroll
        for (int ks = 0; ks < 8; ks++) {
            bf16x8 bfrag = bp[ks * 64];
            acc = __builtin_amdgcn_mfma_f32_16x16x32_bf16(afrag[ks], bfrag, acc, 0, 0, 0);
        }
        bf16x4 hv;
#pragma unroll
        for (int r = 0; r < 4; r++) hv[r] = (bf16_t)acc[r];
        xz2[((size_t)(t * 4 + w) * 64 + ntg) * 64 + lane] = hv;
    }
}

__device__ __forceinline__ float sigmoid_f(float z) {
    return 1.0f / (1.0f + __expf(-z));
}
__device__ __forceinline__ float tanh_f(float z) {
    float e = __expf(2.0f * z);
    return 1.0f - 2.0f / (e + 1.0f);
}
__device__ __forceinline__ unsigned pack2(float a, float b) {
    unsigned short xs = __builtin_bit_cast(unsigned short, (bf16_t)a);
    unsigned short ys = __builtin_bit_cast(unsigned short, (bf16_t)b);
    return (unsigned)xs | ((unsigned)ys << 16);
}
__device__ __forceinline__ bf16_t unpk_lo(unsigned v) {
    return __builtin_bit_cast(bf16_t, (unsigned short)(v & 0xffffu));
}
__device__ __forceinline__ bf16_t unpk_hi(unsigned v) {
    return __builtin_bit_cast(bf16_t, (unsigned short)(v >> 16));
}

// MFMA with B operand in AGPR class (gfx950: A/B may come from AGPRs).
__device__ __forceinline__ void mfma_aB(f32x4& d, bf16x8 a, bf16x8 b) {
    asm("v_mfma_f32_16x16x32_bf16 %0, %1, %2, %0" : "+v"(d) : "v"(a), "a"(b));
}

__device__ __forceinline__ bool valid_q(u64 q, unsigned key) {
    return ((unsigned)(q >> 32)) == (((unsigned)q) ^ key);
}

// LDS-only barrier: drain LDS ops, sync waves (mid-step; no vmem pending).
__device__ __forceinline__ void lds_barrier() {
    asm volatile("s_waitcnt lgkmcnt(0)\n\ts_barrier" ::: "memory");
}

// ---------------------------------------------------------------------------
// Phase B: recurrence. Grid: 16 blocks x 512 thr (8 waves); blocks with
// (b&4) exit. Worker b: group g=b&3 (batches 16g..16g+16), half p=b>>3
// (units 128p..128p+128); partner = b^8. Wave w owns unit-tile p*8+w:
// ureg[4][8] in AGPRs, 32 MFMAs/step, gates/c/h in-register.
// Exchange: R6-verified epoch-keyed u64 {data, data^key} agent atomics;
// split-K hides the poll under own-half MFMAs; __syncthreads (vmcnt drain)
// after publish makes h(t) visible before any wave leaves step t.
// ---------------------------------------------------------------------------
__global__ __launch_bounds__(512, 2) void lstm_pair(const bf16x4* __restrict__ xz2,
                                                    const bf16_t* __restrict__ Up,
                                                    u64* __restrict__ exch,
                                                    float* __restrict__ hfin) {
    if (blockIdx.x & 4) return;           // spares (XCD-placement trick)
    const int g    = blockIdx.x & 3;
    const int p    = (blockIdx.x >> 3) & 1;
    const int w    = threadIdx.x >> 6;
    const int lane = threadIdx.x & 63;
    const int l15  = lane & 15;
    const int quad = lane >> 4;

    __shared__ __align__(16) bf16_t h_lds[2][16][264];

    // ---- U-slice -> AGPRs (once) -------------------------------------------
    const bf16x8* Uf = (const bf16x8*)Up + lane;
    bf16x8 u[4][8];
#pragma unroll
    for (int G = 0; G < 4; G++) {
        int ntg = G * 16 + p * 8 + w;
#pragma unroll
        for (int ks = 0; ks < 8; ks++)
            u[G][ks] = Uf[(ntg * 8 + ks) * 64];
    }
    asm volatile("" : "+a"(u[0][0]), "+a"(u[0][1]), "+a"(u[0][2]), "+a"(u[0][3]),
                      "+a"(u[0][4]), "+a"(u[0][5]), "+a"(u[0][6]), "+a"(u[0][7]));
    asm volatile("" : "+a"(u[1][0]), "+a"(u[1][1]), "+a"(u[1][2]), "+a"(u[1][3]),
                      "+a"(u[1][4]), "+a"(u[1][5]), "+a"(u[1][6]), "+a"(u[1][7]));
    asm volatile("" : "+a"(u[2][0]), "+a"(u[2][1]), "+a"(u[2][2]), "+a"(u[2][3]),
                      "+a"(u[2][4]), "+a"(u[2][5]), "+a"(u[2][6]), "+a"(u[2][7]));
    asm volatile("" : "+a"(u[3][0]), "+a"(u[3][1]), "+a"(u[3][2]), "+a"(u[3][3]),
                      "+a"(u[3][4]), "+a"(u[3][5]), "+a"(u[3][6]), "+a"(u[3][7]));

    for (int i = threadIdx.x; i < 2 * 16 * 264; i += 512)
        (&h_lds[0][0][0])[i] = (bf16_t)0.0f;      // h0 = 0 (both buffers)

    f32x4 cst = {0.f, 0.f, 0.f, 0.f};   // c: batch quad*4+r, unit p*128+w*16+l15

    bf16x4 xzv[4];
#pragma unroll
    for (int G = 0; G < 4; G++)
        xzv[G] = xz2[((size_t)(0 * 4 + g) * 64 + (G * 16 + p * 8 + w)) * 64 + lane];

    __syncthreads();

    const unsigned i0 = (unsigned)threadIdx.x * 2u;   // poll: u64s {i0, i0+1}

    for (int t = 0; t < T_SZ; t++) {
        const int buf  = t & 1;
        const int nbuf = buf ^ 1;

        // ---- 1a: early-issue poll loads for partner h(t-1) -----------------
        const int tp = t - 1;
        const unsigned pkey  = ((unsigned)(tp >> 3) + 1u) << 24;
        const unsigned pbase = (((unsigned)(tp & 7) * 4 + (unsigned)g) * 2 + (unsigned)(1 - p)) * 1024u;
        u64 pq0 = 0, pq1 = 0;
        if (t > 0) {
            pq0 = __hip_atomic_load(&exch[pbase + i0],     __ATOMIC_RELAXED, __HIP_MEMORY_SCOPE_AGENT);
            pq1 = __hip_atomic_load(&exch[pbase + i0 + 1], __ATOMIC_RELAXED, __HIP_MEMORY_SCOPE_AGENT);
        }

        // ---- 1b: own-half A-frags of h(t-1) --------------------------------
        bf16x8 af[8];
#pragma unroll
        for (int k2 = 0; k2 < 4; k2++) {
            const int ks = p * 4 + k2;
            af[ks] = *(const bf16x8*)&h_lds[buf][l15][ks * 32 + quad * 8];
        }

        // ---- 2: acc = xz(t); own-half MFMAs (poll loads in flight) ---------
        f32x4 acc[4];
#pragma unroll
        for (int G = 0; G < 4; G++) {
            bf16x4 xv = xzv[G];
            f32x4 a = {(float)xv[0], (float)xv[1], (float)xv[2], (float)xv[3]};
            acc[G] = a;
        }
#pragma unroll
        for (int k2 = 0; k2 < 4; k2++) {
            const int ks = p * 4 + k2;
#pragma unroll
            for (int G = 0; G < 4; G++)
                mfma_aB(acc[G], af[ks], u[G][ks]);
        }

        // ---- 3: validate poll; write partner half of h(t-1) into LDS[buf] --
        if (t > 0) {
            if (!(valid_q(pq0, pkey) && valid_q(pq1, pkey))) {
                int it = 0;
                unsigned guard = 0;
                do {
                    if (++it > 16) __builtin_amdgcn_s_sleep(1);
                    if (++guard > (1u << 16)) break;   // loud failure, no hang
                    pq0 = __hip_atomic_load(&exch[pbase + i0],     __ATOMIC_RELAXED, __HIP_MEMORY_SCOPE_AGENT);
                    pq1 = __hip_atomic_load(&exch[pbase + i0 + 1], __ATOMIC_RELAXED, __HIP_MEMORY_SCOPE_AGENT);
                } while (!(valid_q(pq0, pkey) && valid_q(pq1, pkey)));
            }
            const unsigned d0 = (unsigned)pq0, d1 = (unsigned)pq1;
            // i0 -> unit ul=i0>>3, qq=(i0&7)>>1; d0 = batches qq*4+{0,1},
            // d1 = batches qq*4+{2,3} (same ul, qq)
            const int ul  = (int)(i0 >> 3);
            const int qq  = (int)((i0 & 7) >> 1);
            const int col = (1 - p) * 128 + ul;
            h_lds[buf][qq * 4 + 0][col] = unpk_lo(d0);
            h_lds[buf][qq * 4 + 1][col] = unpk_hi(d0);
            h_lds[buf][qq * 4 + 2][col] = unpk_lo(d1);
            h_lds[buf][qq * 4 + 3][col] = unpk_hi(d1);
        }
        lds_barrier();   // partner half of LDS[buf] complete

        // ---- 4: partner-half frags; xz(t+1) prefetch; partner MFMAs --------
#pragma unroll
        for (int k2 = 0; k2 < 4; k2++) {
            const int ks = (1 - p) * 4 + k2;
            af[ks] = *(const bf16x8*)&h_lds[buf][l15][ks * 32 + quad * 8];
        }
        if (t + 1 < T_SZ) {
#pragma unroll
            for (int G = 0; G < 4; G++)
                xzv[G] = xz2[((size_t)((t + 1) * 4 + g) * 64 + (G * 16 + p * 8 + w)) * 64 + lane];
        }
#pragma unroll
        for (int k2 = 0; k2 < 4; k2++) {
            const int ks = (1 - p) * 4 + k2;
#pragma unroll
            for (int G = 0; G < 4; G++)
                mfma_aB(acc[G], af[ks], u[G][ks]);
        }

        // ---- 5: gates ------------------------------------------------------
        float hv[4];
#pragma unroll
        for (int r = 0; r < 4; r++) {
            float ig = sigmoid_f(acc[0][r]);
            float fg = sigmoid_f(acc[1][r]);
            float gg = tanh_f(acc[2][r]);
            float og = sigmoid_f(acc[3][r]);
            float cn = fg * cst[r] + ig * gg;
            cst[r] = cn;
            hv[r] = og * tanh_f(cn);
        }

        if (t == T_SZ - 1) {   // uniform exit
#pragma unroll
            for (int r = 0; r < 4; r++)
                hfin[(g * 16 + quad * 4 + r) * HID + p * 128 + w * 16 + l15] = hv[r];
            break;
        }

        // ---- 6: publish h(t) (agent atomics), own half -> LDS[nbuf] --------
        {
            const unsigned key   = ((unsigned)(t >> 3) + 1u) << 24;
            const unsigned sbase = (((unsigned)(t & 7) * 4 + (unsigned)g) * 2 + (unsigned)p) * 1024u;
            const unsigned ui    = (unsigned)(w * 16 + l15) * 8u + (unsigned)(quad * 2);
            unsigned dw0 = pack2(hv[0], hv[1]);
            unsigned dw1 = pack2(hv[2], hv[3]);
            u64 q0 = (u64)dw0 | ((u64)(dw0 ^ key) << 32);
            u64 q1 = (u64)dw1 | ((u64)(dw1 ^ key) << 32);
            __hip_atomic_store(&exch[sbase + ui],     q0, __ATOMIC_RELAXED, __HIP_MEMORY_SCOPE_AGENT);
            __hip_atomic_store(&exch[sbase + ui + 1], q1, __ATOMIC_RELAXED, __HIP_MEMORY_SCOPE_AGENT);
        }

#pragma unroll
        for (int r = 0; r < 4; r++)
            h_lds[nbuf][quad * 4 + r][p * 128 + w * 16 + l15] = (bf16_t)hv[r];

        // ---- 7: end of step: __syncthreads = vmcnt(0) drain + barrier ------
        // The drain IS the publication: h(t) is visible at the coherence
        // point before any wave proceeds, so the partner's first poll at
        // its step t+1 hits.  (R10 stripped this -> 4x slower.)
        __syncthreads();
    }
}

// ---------------------------------------------------------------------------
// Phase C: logits = h_T @ Wd + bd; softmax. One block per batch row.
// ---------------------------------------------------------------------------
__global__ void head(const float* __restrict__ hfin, const float* __restrict__ Wd,
                     const float* __restrict__ bd, float* __restrict__ out) {
    __shared__ float hrow[HID];
    __shared__ float lg[32];
    __shared__ float ex[32];
    int b = blockIdx.x, tid = threadIdx.x;   // 64 threads
    for (int i = tid; i < HID; i += 64) hrow[i] = hfin[b * HID + i];
    __syncthreads();
    if (tid < NCLS) {
        float acc = bd[tid];
        for (int k = 0; k < HID; k++) acc = fmaf(hrow[k], Wd[k * NCLS + tid], acc);
        lg[tid] = acc;
    }
    __syncthreads();
    if (tid < NCLS) {
        float m = -1e30f;
        for (int jj = 0; jj < NCLS; jj++) m = fmaxf(m, lg[jj]);
        ex[tid] = __expf(lg[tid] - m);
    }
    __syncthreads();
    if (tid < NCLS) {
        float sden = 0.0f;
        for (int jj = 0; jj < NCLS; jj++) sden += ex[jj];
        out[b * NCLS + tid] = ex[tid] / sden;
    }
}

// ---------------------------------------------------------------------------
extern "C" void kernel_launch(void* const* d_in, const int* in_sizes, int n_in,
                              void* d_out, int out_size, void* d_ws, size_t ws_size,
                              hipStream_t stream) {
    const int*   x    = (const int*)d_in[0];
    const float* emb  = (const float*)d_in[1];
    const float* W    = (const float*)d_in[2];
    const float* U    = (const float*)d_in[3];
    const float* bias = (const float*)d_in[4];
    const float* Wd   = (const float*)d_in[5];
    const float* bd   = (const float*)d_in[6];
    float* out = (float*)d_out;

    char* ws = (char*)d_ws;
    bf16_t* Up   = (bf16_t*)(ws + WS_UPACK);
    bf16_t* Wp   = (bf16_t*)(ws + WS_WPACK);
    float*  hf   = (float*)(ws + WS_HFIN);
    u64*    exch = (u64*)(ws + WS_EXCH);
    bf16x4* xz2  = (bf16x4*)(ws + WS_XZ);

    pack_weights<<<dim3(1024), dim3(256), 0, stream>>>(W, U, Wp, Up);
    xz_gemm<<<dim3(4096), dim3(256), 0, stream>>>(x, emb, Wp, bias, xz2);
    lstm_pair<<<dim3(16), dim3(512), 0, stream>>>(xz2, Up, exch, hf);
    head<<<dim3(64), dim3(64), 0, stream>>>(hf, Wd, bd, out);
}

// Round 6
// 1456.775 us; speedup vs baseline: 3.7410x; 3.7410x over previous
//
#include <hip/hip_runtime.h>
#include <hip/hip_bf16.h>
#include <math.h>

// ---------------------------------------------------------------------------
// LSTM text classifier forward, MI355X/gfx950.  Round 12 = byte-exact R6
// restoration (session-verified optimum: 1458 us total, lstm_pair 1292 us).
//
// Session findings that close the design space (R7-R11):
//  - Single-CU full-U is register-infeasible: U = 131072 dwords needs the
//    register files of >=1024 threads, which caps at 128 regs/thread --
//    zero working set.  The 2-CU pair is forced.
//  - Streaming U from L2 via LDS is LDS-BW-bound (512 KB/step / 85 B/cy
//    ~ 6170 cyc/step) -- worse than the exchange.
//  - sc0/L2 producer-consumer channel does not work at HIP level (R8/R9).
//  - Lag-1 split-K overlap runs 4x SLOWER regardless of drain placement
//    (R10/R11): identical absolute VALU/MFMA busy, +4000us of dead wait.
//    Same-step exchange acts as a per-step rendezvous (tight phase lock);
//    removing it lets inter-block skew wander and stalls dominate.
//  - R6's epoch-keyed same-step exchange is the best of 6 variants tried.
//
// Structure: 8 worker blocks = 4 batch-groups x 2 halves (128 units);
// U in AGPRs via "+a" pin + inline-asm MFMA (B from AGPR); h double-
// buffered in LDS; partner blocks b,b^8 (same XCD under %8 rr; blocks
// with b&4 exit as spares).  Exchange: epoch-keyed mirror u64
// {data, data^key}, key=((t>>3)+1)<<24, ring slot t%8, agent atomics.
//
// MFMA 16x16x32 bf16 layouts (m89/m91):
//   A[m][k]: m=lane&15, k=(lane>>4)*8+j      B[k][n]: n=lane&15, same k
//   C/D:     col=lane&15, row=(lane>>4)*4+reg
// ---------------------------------------------------------------------------

typedef __bf16 bf16_t;
typedef bf16_t bf16x8 __attribute__((ext_vector_type(8)));
typedef bf16_t bf16x4 __attribute__((ext_vector_type(4)));
typedef float  f32x4  __attribute__((ext_vector_type(4)));
typedef unsigned long long u64;

#define T_SZ 512
#define HID 256
#define G4 1024
#define NCLS 20

// workspace layout (bytes)
#define WS_UPACK 0u
#define WS_WPACK (512u * 1024u)
#define WS_HFIN  (1024u * 1024u)                  // 64 KB
#define WS_EXCH  (1536u * 1024u)                  // 512 KB: 8 slots x 4g x 2p x 1024 u64
#define WS_XZ    (2u * 1024u * 1024u)             // 64 MB
// total: 66 MB

// ---------------------------------------------------------------------------
// Pack W and U (f32 [256][1024]) into bf16 B-fragment order:
// frag f = (ntile*8 + kstep)*64 + lane ; element j=0..7
// value = M[kstep*32 + (lane>>4)*8 + j][ntile*16 + (lane&15)]
// ---------------------------------------------------------------------------
__global__ void pack_weights(const float* __restrict__ W, const float* __restrict__ U,
                             bf16_t* __restrict__ Wp, bf16_t* __restrict__ Up) {
    int tid  = blockIdx.x * blockDim.x + threadIdx.x;   // 0..262143
    int j    = tid & 7;
    int lane = (tid >> 3) & 63;
    int ks   = (tid >> 9) & 7;
    int nt   = tid >> 12;
    int row  = ks * 32 + ((lane >> 4) << 3) + j;
    int col  = nt * 16 + (lane & 15);
    Wp[tid] = (bf16_t)W[row * G4 + col];
    Up[tid] = (bf16_t)U[row * G4 + col];
}

// ---------------------------------------------------------------------------
// Phase A: xz = emb[x] @ W + bias, stored bf16 in C-fragment order:
//   xz2[((t*4 + bchunk)*64 + ntile)*64 + lane] = bf16x4 {r=0..3}
// value[r] = z[batch = bchunk*16 + (lane>>4)*4 + r][col = ntile*16 + (lane&15)]
// ---------------------------------------------------------------------------
__global__ __launch_bounds__(256) void xz_gemm(const int* __restrict__ x,
                                               const float* __restrict__ emb,
                                               const bf16_t* __restrict__ Wp,
                                               const float* __restrict__ bias,
                                               bf16x4* __restrict__ xz2) {
    int nb   = blockIdx.x & 7;
    int t    = blockIdx.x >> 3;
    int w    = threadIdx.x >> 6;
    int lane = threadIdx.x & 63;
    int l15  = lane & 15;
    int quad = lane >> 4;

    int b_row = w * 16 + l15;
    int tok   = x[b_row * T_SZ + t];
    const float* erow = emb + (size_t)tok * 256;

    bf16x8 afrag[8];
#pragma unroll
    for (int ks = 0; ks < 8; ks++) {
        const float4* p = (const float4*)(erow + ks * 32 + quad * 8);
        float4 v0 = p[0], v1 = p[1];
        bf16x8 a;
        a[0] = (bf16_t)v0.x; a[1] = (bf16_t)v0.y; a[2] = (bf16_t)v0.z; a[3] = (bf16_t)v0.w;
        a[4] = (bf16_t)v1.x; a[5] = (bf16_t)v1.y; a[6] = (bf16_t)v1.z; a[7] = (bf16_t)v1.w;
        afrag[ks] = a;
    }

    const bf16x8* Wf = (const bf16x8*)Wp;

#pragma unroll
    for (int nt = 0; nt < 8; nt++) {
        int ntg = nb * 8 + nt;
        float bv = bias[ntg * 16 + l15];
        f32x4 acc = {bv, bv, bv, bv};
        const bf16x8* bp = Wf + (size_t)(ntg * 8) * 64 + lane;
#pragma unroll
        for (int ks = 0; ks < 8; ks++) {
            bf16x8 bfrag = bp[ks * 64];
            acc = __builtin_amdgcn_mfma_f32_16x16x32_bf16(afrag[ks], bfrag, acc, 0, 0, 0);
        }
        bf16x4 hv;
#pragma unroll
        for (int r = 0; r < 4; r++) hv[r] = (bf16_t)acc[r];
        xz2[((size_t)(t * 4 + w) * 64 + ntg) * 64 + lane] = hv;
    }
}

__device__ __forceinline__ float sigmoid_f(float z) {
    return 1.0f / (1.0f + __expf(-z));
}
__device__ __forceinline__ float tanh_f(float z) {
    float e = __expf(2.0f * z);
    return 1.0f - 2.0f / (e + 1.0f);
}
__device__ __forceinline__ unsigned pack2(float a, float b) {
    unsigned short xs = __builtin_bit_cast(unsigned short, (bf16_t)a);
    unsigned short ys = __builtin_bit_cast(unsigned short, (bf16_t)b);
    return (unsigned)xs | ((unsigned)ys << 16);
}
__device__ __forceinline__ bf16_t unpk_lo(unsigned v) {
    return __builtin_bit_cast(bf16_t, (unsigned short)(v & 0xffffu));
}
__device__ __forceinline__ bf16_t unpk_hi(unsigned v) {
    return __builtin_bit_cast(bf16_t, (unsigned short)(v >> 16));
}

// MFMA with B operand in AGPR class (gfx950: A/B may come from AGPRs).
__device__ __forceinline__ void mfma_aB(f32x4& d, bf16x8 a, bf16x8 b) {
    asm("v_mfma_f32_16x16x32_bf16 %0, %1, %2, %0" : "+v"(d) : "v"(a), "a"(b));
}

// ---------------------------------------------------------------------------
// Phase B: recurrence. Grid: 16 blocks x 512 thr (8 waves); blocks with
// (b&4) exit. Worker b: group g=b&3 (batches 16g..16g+16), half p=b>>3
// (units 128p..128p+128); partner = b^8. Wave w owns unit-tile p*8+w:
// ureg[4][8] in AGPRs, 32 MFMAs/step, gates/c/h in-register.
// Exchange: epoch-keyed u64 {data, data^key} handshake (see header).
// ---------------------------------------------------------------------------
__global__ __launch_bounds__(512, 2) void lstm_pair(const bf16x4* __restrict__ xz2,
                                                    const bf16_t* __restrict__ Up,
                                                    u64* __restrict__ exch,
                                                    float* __restrict__ hfin) {
    if (blockIdx.x & 4) return;           // spares (XCD-placement trick)
    const int g    = blockIdx.x & 3;
    const int p    = (blockIdx.x >> 3) & 1;
    const int w    = threadIdx.x >> 6;
    const int lane = threadIdx.x & 63;
    const int l15  = lane & 15;
    const int quad = lane >> 4;

    __shared__ __align__(16) bf16_t h_lds[2][16][264];

    // ---- U-slice -> AGPRs (once) -------------------------------------------
    const bf16x8* Uf = (const bf16x8*)Up + lane;
    bf16x8 u[4][8];
#pragma unroll
    for (int G = 0; G < 4; G++) {
        int ntg = G * 16 + p * 8 + w;
#pragma unroll
        for (int ks = 0; ks < 8; ks++)
            u[G][ks] = Uf[(ntg * 8 + ks) * 64];
    }
    asm volatile("" : "+a"(u[0][0]), "+a"(u[0][1]), "+a"(u[0][2]), "+a"(u[0][3]),
                      "+a"(u[0][4]), "+a"(u[0][5]), "+a"(u[0][6]), "+a"(u[0][7]));
    asm volatile("" : "+a"(u[1][0]), "+a"(u[1][1]), "+a"(u[1][2]), "+a"(u[1][3]),
                      "+a"(u[1][4]), "+a"(u[1][5]), "+a"(u[1][6]), "+a"(u[1][7]));
    asm volatile("" : "+a"(u[2][0]), "+a"(u[2][1]), "+a"(u[2][2]), "+a"(u[2][3]),
                      "+a"(u[2][4]), "+a"(u[2][5]), "+a"(u[2][6]), "+a"(u[2][7]));
    asm volatile("" : "+a"(u[3][0]), "+a"(u[3][1]), "+a"(u[3][2]), "+a"(u[3][3]),
                      "+a"(u[3][4]), "+a"(u[3][5]), "+a"(u[3][6]), "+a"(u[3][7]));

    for (int i = threadIdx.x; i < 2 * 16 * 264; i += 512)
        (&h_lds[0][0][0])[i] = (bf16_t)0.0f;      // h0 = 0 (both buffers)

    f32x4 cst = {0.f, 0.f, 0.f, 0.f};   // c: batch quad*4+r, unit p*128+w*16+l15

    bf16x4 xzv[4];
#pragma unroll
    for (int G = 0; G < 4; G++)
        xzv[G] = xz2[((size_t)(0 * 4 + g) * 64 + (G * 16 + p * 8 + w)) * 64 + lane];

    __syncthreads();

    for (int t = 0; t < T_SZ; t++) {
        const int buf  = t & 1;
        const int nbuf = buf ^ 1;
        const unsigned key = ((unsigned)(t >> 3) + 1u) << 24;   // epoch key != 0

        // A-frags (full 256-unit h) from current buffer
        bf16x8 af[8];
#pragma unroll
        for (int ks = 0; ks < 8; ks++)
            af[ks] = *(const bf16x8*)&h_lds[buf][l15][ks * 32 + quad * 8];

        f32x4 acc[4];
#pragma unroll
        for (int G = 0; G < 4; G++) {
            bf16x4 xv = xzv[G];
            f32x4 a = {(float)xv[0], (float)xv[1], (float)xv[2], (float)xv[3]};
            acc[G] = a;
        }
#pragma unroll
        for (int ks = 0; ks < 8; ks++)
#pragma unroll
            for (int G = 0; G < 4; G++)
                mfma_aB(acc[G], af[ks], u[G][ks]);

        if (t + 1 < T_SZ) {   // prefetch next xz
#pragma unroll
            for (int G = 0; G < 4; G++)
                xzv[G] = xz2[((size_t)((t + 1) * 4 + g) * 64 + (G * 16 + p * 8 + w)) * 64 + lane];
        }

        float hv[4];
#pragma unroll
        for (int r = 0; r < 4; r++) {
            float ig = sigmoid_f(acc[0][r]);
            float fg = sigmoid_f(acc[1][r]);
            float gg = tanh_f(acc[2][r]);
            float og = sigmoid_f(acc[3][r]);
            float cn = fg * cst[r] + ig * gg;
            cst[r] = cn;
            hv[r] = og * tanh_f(cn);
        }

        if (t == T_SZ - 1) {   // uniform exit
#pragma unroll
            for (int r = 0; r < 4; r++)
                hfin[(g * 16 + quad * 4 + r) * HID + p * 128 + w * 16 + l15] = hv[r];
            break;
        }

        // publish FIRST (start propagation), then local LDS write
        {
            unsigned dw0 = pack2(hv[0], hv[1]);
            unsigned dw1 = pack2(hv[2], hv[3]);
            u64 q0 = (u64)dw0 | ((u64)(dw0 ^ key) << 32);
            u64 q1 = (u64)dw1 | ((u64)(dw1 ^ key) << 32);
            unsigned base = (((unsigned)(t & 7) * 4 + (unsigned)g) * 2 + (unsigned)p) * 1024u;
            unsigned ui   = (unsigned)(w * 16 + l15) * 8u + (unsigned)(quad * 2);
            __hip_atomic_store(&exch[base + ui],     q0, __ATOMIC_RELAXED, __HIP_MEMORY_SCOPE_AGENT);
            __hip_atomic_store(&exch[base + ui + 1], q1, __ATOMIC_RELAXED, __HIP_MEMORY_SCOPE_AGENT);
        }

#pragma unroll
        for (int r = 0; r < 4; r++)
            h_lds[nbuf][quad * 4 + r][p * 128 + w * 16 + l15] = (bf16_t)hv[r];

        // poll partner's half: thread handles u64s {2*tid, 2*tid+1}
        {
            unsigned pbase = (((unsigned)(t & 7) * 4 + (unsigned)g) * 2 + (unsigned)(1 - p)) * 1024u;
            unsigned i0 = (unsigned)threadIdx.x * 2u;
            u64 q0, q1;
            for (;;) {
                q0 = __hip_atomic_load(&exch[pbase + i0],     __ATOMIC_RELAXED, __HIP_MEMORY_SCOPE_AGENT);
                q1 = __hip_atomic_load(&exch[pbase + i0 + 1], __ATOMIC_RELAXED, __HIP_MEMORY_SCOPE_AGENT);
                bool v0 = ((unsigned)(q0 >> 32)) == (((unsigned)q0) ^ key);
                bool v1 = ((unsigned)(q1 >> 32)) == (((unsigned)q1) ^ key);
                if (v0 && v1) break;
            }
            unsigned d0 = (unsigned)q0, d1 = (unsigned)q1;
            // i0 -> unit ul=i0>>3, qq=(i0&7)>>1; i0 even: d0 = batches qq*4+{0,1},
            // d1 = batches qq*4+{2,3} (same ul, qq)
            int ul  = (int)(i0 >> 3);
            int qq  = (int)((i0 & 7) >> 1);
            int col = (1 - p) * 128 + ul;
            h_lds[nbuf][qq * 4 + 0][col] = unpk_lo(d0);
            h_lds[nbuf][qq * 4 + 1][col] = unpk_hi(d0);
            h_lds[nbuf][qq * 4 + 2][col] = unpk_lo(d1);
            h_lds[nbuf][qq * 4 + 3][col] = unpk_hi(d1);
        }

        __syncthreads();   // next h buffer complete
    }
}

// ---------------------------------------------------------------------------
// Phase C: logits = h_T @ Wd + bd; softmax. One block per batch row.
// ---------------------------------------------------------------------------
__global__ void head(const float* __restrict__ hfin, const float* __restrict__ Wd,
                     const float* __restrict__ bd, float* __restrict__ out) {
    __shared__ float hrow[HID];
    __shared__ float lg[32];
    __shared__ float ex[32];
    int b = blockIdx.x, tid = threadIdx.x;   // 64 threads
    for (int i = tid; i < HID; i += 64) hrow[i] = hfin[b * HID + i];
    __syncthreads();
    if (tid < NCLS) {
        float acc = bd[tid];
        for (int k = 0; k < HID; k++) acc = fmaf(hrow[k], Wd[k * NCLS + tid], acc);
        lg[tid] = acc;
    }
    __syncthreads();
    if (tid < NCLS) {
        float m = -1e30f;
        for (int jj = 0; jj < NCLS; jj++) m = fmaxf(m, lg[jj]);
        ex[tid] = __expf(lg[tid] - m);
    }
    __syncthreads();
    if (tid < NCLS) {
        float sden = 0.0f;
        for (int jj = 0; jj < NCLS; jj++) sden += ex[jj];
        out[b * NCLS + tid] = ex[tid] / sden;
    }
}

// ---------------------------------------------------------------------------
extern "C" void kernel_launch(void* const* d_in, const int* in_sizes, int n_in,
                              void* d_out, int out_size, void* d_ws, size_t ws_size,
                              hipStream_t stream) {
    const int*   x    = (const int*)d_in[0];
    const float* emb  = (const float*)d_in[1];
    const float* W    = (const float*)d_in[2];
    const float* U    = (const float*)d_in[3];
    const float* bias = (const float*)d_in[4];
    const float* Wd   = (const float*)d_in[5];
    const float* bd   = (const float*)d_in[6];
    float* out = (float*)d_out;

    char* ws = (char*)d_ws;
    bf16_t* Up   = (bf16_t*)(ws + WS_UPACK);
    bf16_t* Wp   = (bf16_t*)(ws + WS_WPACK);
    float*  hf   = (float*)(ws + WS_HFIN);
    u64*    exch = (u64*)(ws + WS_EXCH);
    bf16x4* xz2  = (bf16x4*)(ws + WS_XZ);

    pack_weights<<<dim3(1024), dim3(256), 0, stream>>>(W, U, Wp, Up);
    xz_gemm<<<dim3(4096), dim3(256), 0, stream>>>(x, emb, Wp, bias, xz2);
    lstm_pair<<<dim3(16), dim3(512), 0, stream>>>(xz2, Up, exch, hf);
    head<<<dim3(64), dim3(64), 0, stream>>>(hf, Wd, bd, out);
}

// Round 7
// 1412.067 us; speedup vs baseline: 3.8594x; 1.0317x over previous
//
#include <hip/hip_runtime.h>
#include <hip/hip_bf16.h>
#include <math.h>

// ---------------------------------------------------------------------------
// LSTM text classifier forward, MI355X/gfx950.  Round 13.
//
// R12 = R6 restoration, verified (1456.8us total, lstm_pair 1292us).
//
// R13 theory -- the mutual lazy-drain standoff: in R6/R12 the publish
// stores are only force-drained by the vmcnt(0) inside the END-of-step
// __syncthreads, which runs AFTER the poll loop.  During the poll window
// neither partner's stores are guaranteed at the coherence point; both
// blocks spin on L3 loads while their own stores drain lazily -> 2-4
// wasted L3 round trips/step (~the unexplained 4000 cyc).  R11 (drain at
// the barrier, still after the poll) changing nothing is consistent.
//
// R13 = R12 + ONE insertion: explicit s_waitcnt vmcnt(0) right after the
// publish stores (own LDS write placed before it -- lgkm counter, hides
// under the drain).  Both partners drain symmetrically BEFORE polling ->
// first poll hits.  Pure timing; protocol byte-identical to the verified
// kernel.  No correctness or hang surface.
//
// Structure: 8 worker blocks = 4 batch-groups x 2 halves (128 units);
// U in AGPRs via "+a" pin + inline-asm MFMA (B from AGPR); h double-
// buffered in LDS; partner blocks b,b^8 (same XCD under %8 rr; blocks
// with b&4 exit as spares).  Exchange: epoch-keyed mirror u64
// {data, data^key}, key=((t>>3)+1)<<24, ring slot t%8, agent atomics.
//
// MFMA 16x16x32 bf16 layouts (m89/m91):
//   A[m][k]: m=lane&15, k=(lane>>4)*8+j      B[k][n]: n=lane&15, same k
//   C/D:     col=lane&15, row=(lane>>4)*4+reg
// ---------------------------------------------------------------------------

typedef __bf16 bf16_t;
typedef bf16_t bf16x8 __attribute__((ext_vector_type(8)));
typedef bf16_t bf16x4 __attribute__((ext_vector_type(4)));
typedef float  f32x4  __attribute__((ext_vector_type(4)));
typedef unsigned long long u64;

#define T_SZ 512
#define HID 256
#define G4 1024
#define NCLS 20

// workspace layout (bytes)
#define WS_UPACK 0u
#define WS_WPACK (512u * 1024u)
#define WS_HFIN  (1024u * 1024u)                  // 64 KB
#define WS_EXCH  (1536u * 1024u)                  // 512 KB: 8 slots x 4g x 2p x 1024 u64
#define WS_XZ    (2u * 1024u * 1024u)             // 64 MB
// total: 66 MB

// ---------------------------------------------------------------------------
// Pack W and U (f32 [256][1024]) into bf16 B-fragment order:
// frag f = (ntile*8 + kstep)*64 + lane ; element j=0..7
// value = M[kstep*32 + (lane>>4)*8 + j][ntile*16 + (lane&15)]
// ---------------------------------------------------------------------------
__global__ void pack_weights(const float* __restrict__ W, const float* __restrict__ U,
                             bf16_t* __restrict__ Wp, bf16_t* __restrict__ Up) {
    int tid  = blockIdx.x * blockDim.x + threadIdx.x;   // 0..262143
    int j    = tid & 7;
    int lane = (tid >> 3) & 63;
    int ks   = (tid >> 9) & 7;
    int nt   = tid >> 12;
    int row  = ks * 32 + ((lane >> 4) << 3) + j;
    int col  = nt * 16 + (lane & 15);
    Wp[tid] = (bf16_t)W[row * G4 + col];
    Up[tid] = (bf16_t)U[row * G4 + col];
}

// ---------------------------------------------------------------------------
// Phase A: xz = emb[x] @ W + bias, stored bf16 in C-fragment order:
//   xz2[((t*4 + bchunk)*64 + ntile)*64 + lane] = bf16x4 {r=0..3}
// value[r] = z[batch = bchunk*16 + (lane>>4)*4 + r][col = ntile*16 + (lane&15)]
// ---------------------------------------------------------------------------
__global__ __launch_bounds__(256) void xz_gemm(const int* __restrict__ x,
                                               const float* __restrict__ emb,
                                               const bf16_t* __restrict__ Wp,
                                               const float* __restrict__ bias,
                                               bf16x4* __restrict__ xz2) {
    int nb   = blockIdx.x & 7;
    int t    = blockIdx.x >> 3;
    int w    = threadIdx.x >> 6;
    int lane = threadIdx.x & 63;
    int l15  = lane & 15;
    int quad = lane >> 4;

    int b_row = w * 16 + l15;
    int tok   = x[b_row * T_SZ + t];
    const float* erow = emb + (size_t)tok * 256;

    bf16x8 afrag[8];
#pragma unroll
    for (int ks = 0; ks < 8; ks++) {
        const float4* p = (const float4*)(erow + ks * 32 + quad * 8);
        float4 v0 = p[0], v1 = p[1];
        bf16x8 a;
        a[0] = (bf16_t)v0.x; a[1] = (bf16_t)v0.y; a[2] = (bf16_t)v0.z; a[3] = (bf16_t)v0.w;
        a[4] = (bf16_t)v1.x; a[5] = (bf16_t)v1.y; a[6] = (bf16_t)v1.z; a[7] = (bf16_t)v1.w;
        afrag[ks] = a;
    }

    const bf16x8* Wf = (const bf16x8*)Wp;

#pragma unroll
    for (int nt = 0; nt < 8; nt++) {
        int ntg = nb * 8 + nt;
        float bv = bias[ntg * 16 + l15];
        f32x4 acc = {bv, bv, bv, bv};
        const bf16x8* bp = Wf + (size_t)(ntg * 8) * 64 + lane;
#pragma unroll
        for (int ks = 0; ks < 8; ks++) {
            bf16x8 bfrag = bp[ks * 64];
            acc = __builtin_amdgcn_mfma_f32_16x16x32_bf16(afrag[ks], bfrag, acc, 0, 0, 0);
        }
        bf16x4 hv;
#pragma unroll
        for (int r = 0; r < 4; r++) hv[r] = (bf16_t)acc[r];
        xz2[((size_t)(t * 4 + w) * 64 + ntg) * 64 + lane] = hv;
    }
}

__device__ __forceinline__ float sigmoid_f(float z) {
    return 1.0f / (1.0f + __expf(-z));
}
__device__ __forceinline__ float tanh_f(float z) {
    float e = __expf(2.0f * z);
    return 1.0f - 2.0f / (e + 1.0f);
}
__device__ __forceinline__ unsigned pack2(float a, float b) {
    unsigned short xs = __builtin_bit_cast(unsigned short, (bf16_t)a);
    unsigned short ys = __builtin_bit_cast(unsigned short, (bf16_t)b);
    return (unsigned)xs | ((unsigned)ys << 16);
}
__device__ __forceinline__ bf16_t unpk_lo(unsigned v) {
    return __builtin_bit_cast(bf16_t, (unsigned short)(v & 0xffffu));
}
__device__ __forceinline__ bf16_t unpk_hi(unsigned v) {
    return __builtin_bit_cast(bf16_t, (unsigned short)(v >> 16));
}

// MFMA with B operand in AGPR class (gfx950: A/B may come from AGPRs).
__device__ __forceinline__ void mfma_aB(f32x4& d, bf16x8 a, bf16x8 b) {
    asm("v_mfma_f32_16x16x32_bf16 %0, %1, %2, %0" : "+v"(d) : "v"(a), "a"(b));
}

// ---------------------------------------------------------------------------
// Phase B: recurrence. Grid: 16 blocks x 512 thr (8 waves); blocks with
// (b&4) exit. Worker b: group g=b&3 (batches 16g..16g+16), half p=b>>3
// (units 128p..128p+128); partner = b^8. Wave w owns unit-tile p*8+w:
// ureg[4][8] in AGPRs, 32 MFMAs/step, gates/c/h in-register.
// Exchange: epoch-keyed u64 {data, data^key} handshake; NEW in R13:
// explicit vmcnt(0) drain after publish, BEFORE the poll (see header).
// ---------------------------------------------------------------------------
__global__ __launch_bounds__(512, 2) void lstm_pair(const bf16x4* __restrict__ xz2,
                                                    const bf16_t* __restrict__ Up,
                                                    u64* __restrict__ exch,
                                                    float* __restrict__ hfin) {
    if (blockIdx.x & 4) return;           // spares (XCD-placement trick)
    const int g    = blockIdx.x & 3;
    const int p    = (blockIdx.x >> 3) & 1;
    const int w    = threadIdx.x >> 6;
    const int lane = threadIdx.x & 63;
    const int l15  = lane & 15;
    const int quad = lane >> 4;

    __shared__ __align__(16) bf16_t h_lds[2][16][264];

    // ---- U-slice -> AGPRs (once) -------------------------------------------
    const bf16x8* Uf = (const bf16x8*)Up + lane;
    bf16x8 u[4][8];
#pragma unroll
    for (int G = 0; G < 4; G++) {
        int ntg = G * 16 + p * 8 + w;
#pragma unroll
        for (int ks = 0; ks < 8; ks++)
            u[G][ks] = Uf[(ntg * 8 + ks) * 64];
    }
    asm volatile("" : "+a"(u[0][0]), "+a"(u[0][1]), "+a"(u[0][2]), "+a"(u[0][3]),
                      "+a"(u[0][4]), "+a"(u[0][5]), "+a"(u[0][6]), "+a"(u[0][7]));
    asm volatile("" : "+a"(u[1][0]), "+a"(u[1][1]), "+a"(u[1][2]), "+a"(u[1][3]),
                      "+a"(u[1][4]), "+a"(u[1][5]), "+a"(u[1][6]), "+a"(u[1][7]));
    asm volatile("" : "+a"(u[2][0]), "+a"(u[2][1]), "+a"(u[2][2]), "+a"(u[2][3]),
                      "+a"(u[2][4]), "+a"(u[2][5]), "+a"(u[2][6]), "+a"(u[2][7]));
    asm volatile("" : "+a"(u[3][0]), "+a"(u[3][1]), "+a"(u[3][2]), "+a"(u[3][3]),
                      "+a"(u[3][4]), "+a"(u[3][5]), "+a"(u[3][6]), "+a"(u[3][7]));

    for (int i = threadIdx.x; i < 2 * 16 * 264; i += 512)
        (&h_lds[0][0][0])[i] = (bf16_t)0.0f;      // h0 = 0 (both buffers)

    f32x4 cst = {0.f, 0.f, 0.f, 0.f};   // c: batch quad*4+r, unit p*128+w*16+l15

    bf16x4 xzv[4];
#pragma unroll
    for (int G = 0; G < 4; G++)
        xzv[G] = xz2[((size_t)(0 * 4 + g) * 64 + (G * 16 + p * 8 + w)) * 64 + lane];

    __syncthreads();

    for (int t = 0; t < T_SZ; t++) {
        const int buf  = t & 1;
        const int nbuf = buf ^ 1;
        const unsigned key = ((unsigned)(t >> 3) + 1u) << 24;   // epoch key != 0

        // A-frags (full 256-unit h) from current buffer
        bf16x8 af[8];
#pragma unroll
        for (int ks = 0; ks < 8; ks++)
            af[ks] = *(const bf16x8*)&h_lds[buf][l15][ks * 32 + quad * 8];

        f32x4 acc[4];
#pragma unroll
        for (int G = 0; G < 4; G++) {
            bf16x4 xv = xzv[G];
            f32x4 a = {(float)xv[0], (float)xv[1], (float)xv[2], (float)xv[3]};
            acc[G] = a;
        }
#pragma unroll
        for (int ks = 0; ks < 8; ks++)
#pragma unroll
            for (int G = 0; G < 4; G++)
                mfma_aB(acc[G], af[ks], u[G][ks]);

        if (t + 1 < T_SZ) {   // prefetch next xz
#pragma unroll
            for (int G = 0; G < 4; G++)
                xzv[G] = xz2[((size_t)((t + 1) * 4 + g) * 64 + (G * 16 + p * 8 + w)) * 64 + lane];
        }

        float hv[4];
#pragma unroll
        for (int r = 0; r < 4; r++) {
            float ig = sigmoid_f(acc[0][r]);
            float fg = sigmoid_f(acc[1][r]);
            float gg = tanh_f(acc[2][r]);
            float og = sigmoid_f(acc[3][r]);
            float cn = fg * cst[r] + ig * gg;
            cst[r] = cn;
            hv[r] = og * tanh_f(cn);
        }

        if (t == T_SZ - 1) {   // uniform exit
#pragma unroll
            for (int r = 0; r < 4; r++)
                hfin[(g * 16 + quad * 4 + r) * HID + p * 128 + w * 16 + l15] = hv[r];
            break;
        }

        // publish FIRST (start propagation), then local LDS write
        {
            unsigned dw0 = pack2(hv[0], hv[1]);
            unsigned dw1 = pack2(hv[2], hv[3]);
            u64 q0 = (u64)dw0 | ((u64)(dw0 ^ key) << 32);
            u64 q1 = (u64)dw1 | ((u64)(dw1 ^ key) << 32);
            unsigned base = (((unsigned)(t & 7) * 4 + (unsigned)g) * 2 + (unsigned)p) * 1024u;
            unsigned ui   = (unsigned)(w * 16 + l15) * 8u + (unsigned)(quad * 2);
            __hip_atomic_store(&exch[base + ui],     q0, __ATOMIC_RELAXED, __HIP_MEMORY_SCOPE_AGENT);
            __hip_atomic_store(&exch[base + ui + 1], q1, __ATOMIC_RELAXED, __HIP_MEMORY_SCOPE_AGENT);
        }

#pragma unroll
        for (int r = 0; r < 4; r++)
            h_lds[nbuf][quad * 4 + r][p * 128 + w * 16 + l15] = (bf16_t)hv[r];

        // R13: drain publish stores to the coherence point BEFORE polling.
        // (LDS writes above use the independent lgkm counter and hide under
        // this.)  Both partners drain symmetrically -> first poll hits,
        // instead of 2-4 L3 round trips of mutual lazy-drain standoff.
        asm volatile("s_waitcnt vmcnt(0)" ::: "memory");

        // poll partner's half: thread handles u64s {2*tid, 2*tid+1}
        {
            unsigned pbase = (((unsigned)(t & 7) * 4 + (unsigned)g) * 2 + (unsigned)(1 - p)) * 1024u;
            unsigned i0 = (unsigned)threadIdx.x * 2u;
            u64 q0, q1;
            for (;;) {
                q0 = __hip_atomic_load(&exch[pbase + i0],     __ATOMIC_RELAXED, __HIP_MEMORY_SCOPE_AGENT);
                q1 = __hip_atomic_load(&exch[pbase + i0 + 1], __ATOMIC_RELAXED, __HIP_MEMORY_SCOPE_AGENT);
                bool v0 = ((unsigned)(q0 >> 32)) == (((unsigned)q0) ^ key);
                bool v1 = ((unsigned)(q1 >> 32)) == (((unsigned)q1) ^ key);
                if (v0 && v1) break;
            }
            unsigned d0 = (unsigned)q0, d1 = (unsigned)q1;
            // i0 -> unit ul=i0>>3, qq=(i0&7)>>1; i0 even: d0 = batches qq*4+{0,1},
            // d1 = batches qq*4+{2,3} (same ul, qq)
            int ul  = (int)(i0 >> 3);
            int qq  = (int)((i0 & 7) >> 1);
            int col = (1 - p) * 128 + ul;
            h_lds[nbuf][qq * 4 + 0][col] = unpk_lo(d0);
            h_lds[nbuf][qq * 4 + 1][col] = unpk_hi(d0);
            h_lds[nbuf][qq * 4 + 2][col] = unpk_lo(d1);
            h_lds[nbuf][qq * 4 + 3][col] = unpk_hi(d1);
        }

        __syncthreads();   // next h buffer complete
    }
}

// ---------------------------------------------------------------------------
// Phase C: logits = h_T @ Wd + bd; softmax. One block per batch row.
// ---------------------------------------------------------------------------
__global__ void head(const float* __restrict__ hfin, const float* __restrict__ Wd,
                     const float* __restrict__ bd, float* __restrict__ out) {
    __shared__ float hrow[HID];
    __shared__ float lg[32];
    __shared__ float ex[32];
    int b = blockIdx.x, tid = threadIdx.x;   // 64 threads
    for (int i = tid; i < HID; i += 64) hrow[i] = hfin[b * HID + i];
    __syncthreads();
    if (tid < NCLS) {
        float acc = bd[tid];
        for (int k = 0; k < HID; k++) acc = fmaf(hrow[k], Wd[k * NCLS + tid], acc);
        lg[tid] = acc;
    }
    __syncthreads();
    if (tid < NCLS) {
        float m = -1e30f;
        for (int jj = 0; jj < NCLS; jj++) m = fmaxf(m, lg[jj]);
        ex[tid] = __expf(lg[tid] - m);
    }
    __syncthreads();
    if (tid < NCLS) {
        float sden = 0.0f;
        for (int jj = 0; jj < NCLS; jj++) sden += ex[jj];
        out[b * NCLS + tid] = ex[tid] / sden;
    }
}

// ---------------------------------------------------------------------------
extern "C" void kernel_launch(void* const* d_in, const int* in_sizes, int n_in,
                              void* d_out, int out_size, void* d_ws, size_t ws_size,
                              hipStream_t stream) {
    const int*   x    = (const int*)d_in[0];
    const float* emb  = (const float*)d_in[1];
    const float* W    = (const float*)d_in[2];
    const float* U    = (const float*)d_in[3];
    const float* bias = (const float*)d_in[4];
    const float* Wd   = (const float*)d_in[5];
    const float* bd   = (const float*)d_in[6];
    float* out = (float*)d_out;

    char* ws = (char*)d_ws;
    bf16_t* Up   = (bf16_t*)(ws + WS_UPACK);
    bf16_t* Wp   = (bf16_t*)(ws + WS_WPACK);
    float*  hf   = (float*)(ws + WS_HFIN);
    u64*    exch = (u64*)(ws + WS_EXCH);
    bf16x4* xz2  = (bf16x4*)(ws + WS_XZ);

    pack_weights<<<dim3(1024), dim3(256), 0, stream>>>(W, U, Wp, Up);
    xz_gemm<<<dim3(4096), dim3(256), 0, stream>>>(x, emb, Wp, bias, xz2);
    lstm_pair<<<dim3(16), dim3(512), 0, stream>>>(xz2, Up, exch, hf);
    head<<<dim3(64), dim3(64), 0, stream>>>(hf, Wd, bd, out);
}